// Round 12
// baseline (326.451 us; speedup 1.0000x reference)
//
#include <hip/hip_runtime.h>
#include <hip/hip_cooperative_groups.h>
#include <stdint.h>

namespace cg = cooperative_groups;

#define N_NODES 50000
#define N_EDGES 800000
#define D 128
#define DOUT 64

#define CSR_BLK 256
#define CSR_NBLK ((N_NODES + CSR_BLK - 1) / CSR_BLK)  // 196

#define BSH 7                                  // rows per bucket = 128
#define NBUCK ((N_NODES + 127) >> BSH)         // 391
#define EPB 4096                               // edges per bucket_scatter block
#define SC_NBLK ((N_EDGES + EPB - 1) / EPB)    // 196 (== coop grid)

typedef short bf16x8 __attribute__((ext_vector_type(8)));
typedef float f32x4 __attribute__((ext_vector_type(4)));

__host__ __device__ inline uint32_t rotl32(uint32_t v, int d) {
    return (v << d) | (v >> (32 - d));
}

// JAX threefry2x32 (20 rounds), matches jax/_src/prng.py
__host__ __device__ inline void threefry2x32(uint32_t k0, uint32_t k1,
                                             uint32_t x0, uint32_t x1,
                                             uint32_t& o0, uint32_t& o1) {
    uint32_t ks2 = 0x1BD11BDAu ^ k0 ^ k1;
    x0 += k0; x1 += k1;
#define TFR(d) { x0 += x1; x1 = rotl32(x1, d); x1 ^= x0; }
    TFR(13) TFR(15) TFR(26) TFR(6)
    x0 += k1;  x1 += ks2 + 1u;
    TFR(17) TFR(29) TFR(16) TFR(24)
    x0 += ks2; x1 += k0 + 2u;
    TFR(13) TFR(15) TFR(26) TFR(6)
    x0 += k0;  x1 += k1 + 3u;
    TFR(17) TFR(29) TFR(16) TFR(24)
    x0 += k1;  x1 += ks2 + 4u;
    TFR(13) TFR(15) TFR(26) TFR(6)
    x0 += ks2; x1 += k0 + 5u;
#undef TFR
    o0 = x0; o1 = x1;
}

__device__ inline bool keep_mask(uint32_t k0, uint32_t k1, uint32_t j) {
    uint32_t b0, b1;
    threefry2x32(k0, k1, 0u, j, b0, b1);
    uint32_t bits = b0 ^ b1;
    float u = __uint_as_float((bits >> 9) | 0x3f800000u) - 1.0f;
    return u < 0.5f;
}

__device__ inline uint32_t f2bf(float f) {
    uint32_t u = __float_as_uint(f);
    return (u + 0x7fffu + ((u >> 16) & 1u)) >> 16;
}
__device__ inline float bf2f_lo(uint32_t u) { return __uint_as_float(u << 16); }
__device__ inline float bf2f_hi(uint32_t u) { return __uint_as_float(u & 0xffff0000u); }

__device__ inline void fma8(float* a, uint4 u, float w) {
    a[0] = fmaf(w, bf2f_lo(u.x), a[0]);
    a[1] = fmaf(w, bf2f_hi(u.x), a[1]);
    a[2] = fmaf(w, bf2f_lo(u.y), a[2]);
    a[3] = fmaf(w, bf2f_hi(u.y), a[3]);
    a[4] = fmaf(w, bf2f_lo(u.z), a[4]);
    a[5] = fmaf(w, bf2f_hi(u.z), a[5]);
    a[6] = fmaf(w, bf2f_lo(u.w), a[6]);
    a[7] = fmaf(w, bf2f_hi(u.w), a[7]);
}

// ---------------- device phase bodies (shared by coop + fallback) ----------------

__device__ inline void drop8_body(const float* x, ushort* y, uint32_t k0, uint32_t k1, int t) {
    float4 v0 = ((const float4*)x)[t * 2];
    float4 v1 = ((const float4*)x)[t * 2 + 1];
    uint32_t j = (uint32_t)t * 8u;
    float f[8] = {v0.x, v0.y, v0.z, v0.w, v1.x, v1.y, v1.z, v1.w};
    uint32_t o[4];
#pragma unroll
    for (int p = 0; p < 4; ++p) {
        float a = keep_mask(k0, k1, j + 2 * p)     ? f[2 * p] * 2.f     : 0.f;
        float b = keep_mask(k0, k1, j + 2 * p + 1) ? f[2 * p + 1] * 2.f : 0.f;
        o[p] = f2bf(a) | (f2bf(b) << 16);
    }
    ((uint4*)y)[t] = make_uint4(o[0], o[1], o[2], o[3]);
}

__device__ inline void prepw_body(const float* W1, const float* W2,
                                  ushort* W1T, ushort* W2T, int t) {
    if (t < 128 * 128) {
        int n = t >> 7, k = t & 127;
        W1T[n * 128 + k] = (ushort)f2bf(W1[k * 128 + n]);
    } else {
        int u = t - 128 * 128;
        int n = u >> 7, k = u & 127;
        W2T[n * 128 + k] = (ushort)f2bf(W2[k * 64 + n]);
    }
}

// ---------------- ONE cooperative kernel: full CSR build + dropout + weight prep ----------------
__global__ __launch_bounds__(256) void csr_coop(const int* __restrict__ rows,
                                                const int* __restrict__ cols,
                                                const float* __restrict__ w,
                                                const float* __restrict__ X,
                                                const float* __restrict__ W1,
                                                const float* __restrict__ W2,
                                                ushort* __restrict__ Xb,
                                                ushort* __restrict__ W1T,
                                                ushort* __restrict__ W2T,
                                                int* __restrict__ deg,
                                                int* __restrict__ blockSums,
                                                int* __restrict__ blockOff,
                                                int* __restrict__ start,
                                                int* __restrict__ bcur,
                                                int* __restrict__ tmpRow,
                                                int2* __restrict__ tmpCW,
                                                int2* __restrict__ epk,
                                                uint32_t ka0, uint32_t ka1) {
    cg::grid_group grid = cg::this_grid();
    __shared__ int sh[NBUCK];   // reused: red / scan / hist / lcur
    __shared__ int sb[NBUCK];   // base
    int tid = threadIdx.x;
    int gid = blockIdx.x * 256 + tid;
    int gsz = gridDim.x * 256;  // 50176

    // ---- Phase 0: zero deg | dropout(X)->bf16 | weight transpose (independent) ----
    for (int i = gid; i < N_NODES; i += gsz) deg[i] = 0;
    for (int t = gid; t < N_NODES * D / 8; t += gsz) drop8_body(X, Xb, ka0, ka1, t);
    for (int t = gid; t < 128 * 128 + 64 * 128; t += gsz) prepw_body(W1, W2, W1T, W2T, t);
    grid.sync();

    // ---- Phase 1: degree histogram ----
    for (int e = gid; e < N_EDGES; e += gsz) {
        int r = rows[e];
        if (r >= 0 && r < N_NODES) atomicAdd(&deg[r], 1);
    }
    grid.sync();

    // ---- Phase 2: per-block (256-node chunk) sums ----
    {
        int idx = blockIdx.x * 256 + tid;
        sh[tid] = (idx < N_NODES) ? deg[idx] : 0;
        __syncthreads();
        for (int off = 128; off > 0; off >>= 1) {
            if (tid < off) sh[tid] += sh[tid + off];
            __syncthreads();
        }
        if (tid == 0) blockSums[blockIdx.x] = sh[0];
    }
    grid.sync();

    // ---- Phase 3: block 0 scans the 196 chunk sums ----
    if (blockIdx.x == 0) {
        sh[tid] = (tid < CSR_NBLK) ? blockSums[tid] : 0;
        __syncthreads();
        for (int off = 1; off < 256; off <<= 1) {
            int t2 = (tid >= off) ? sh[tid - off] : 0;
            __syncthreads();
            if (tid >= off) sh[tid] += t2;
            __syncthreads();
        }
        if (tid < CSR_NBLK) blockOff[tid] = (tid == 0) ? 0 : sh[tid - 1];
    }
    grid.sync();

    // ---- Phase 4: final scan -> start[], bucket bases -> bcur[] ----
    {
        int idx = blockIdx.x * 256 + tid;
        int d = (idx < N_NODES) ? deg[idx] : 0;
        sh[tid] = d;
        __syncthreads();
        for (int off = 1; off < 256; off <<= 1) {
            int t2 = (tid >= off) ? sh[tid - off] : 0;
            __syncthreads();
            if (tid >= off) sh[tid] += t2;
            __syncthreads();
        }
        int incl = sh[tid];
        int excl = incl - d;
        int boff = blockOff[blockIdx.x];
        if (idx < N_NODES) {
            int s0 = boff + excl;
            start[idx] = s0;
            if ((idx & 127) == 0) bcur[idx >> BSH] = s0;
            if (idx == N_NODES - 1) start[N_NODES] = boff + incl;
        }
    }
    grid.sync();

    // ---- Phase 5: bucket scatter (4096 edges/block) ----
    {
        int e0 = blockIdx.x * EPB;
        for (int i = tid; i < NBUCK; i += 256) sh[i] = 0;
        __syncthreads();
        int myrow[16];
#pragma unroll
        for (int k = 0; k < 16; ++k) {
            int e = e0 + k * 256 + tid;
            int r = (e < N_EDGES) ? rows[e] : -1;
            if (r < 0 || r >= N_NODES) r = -1;   // defensive
            myrow[k] = r;
            if (r >= 0) atomicAdd(&sh[r >> BSH], 1);
        }
        __syncthreads();
        for (int b = tid; b < NBUCK; b += 256) {
            int c = sh[b];
            sb[b] = (c > 0) ? atomicAdd(&bcur[b], c) : 0;
            sh[b] = 0;   // reuse as running offset
        }
        __syncthreads();
#pragma unroll
        for (int k = 0; k < 16; ++k) {
            int r = myrow[k];
            if (r < 0) continue;
            int e = e0 + k * 256 + tid;
            int b = r >> BSH;
            int pos = sb[b] + atomicAdd(&sh[b], 1);
            if (pos < 0 || pos >= N_EDGES) continue;   // defensive
            tmpRow[pos] = r;
            tmpCW[pos] = make_int2(cols[e], __float_as_int(w[e]));
        }
    }
    grid.sync();

    // ---- Phase 6: per-bucket exact placement (LDS cursors) ----
    for (int b = blockIdx.x; b < NBUCK; b += gridDim.x) {
        int r0 = b << BSH;
        int r1 = r0 + (1 << BSH);
        if (r1 > N_NODES) r1 = N_NODES;
        int nr = r1 - r0;
        __syncthreads();
        for (int i = tid; i < nr; i += 256) sh[i] = start[r0 + i];
        __syncthreads();
        int e0 = start[r0], e1 = start[r1];
        for (int i = e0 + tid; i < e1; i += 256) {
            int r = tmpRow[i];
            if (r < r0 || r >= r1) continue;           // defensive
            int pos = atomicAdd(&sh[r - r0], 1);
            if (pos < 0 || pos >= N_EDGES) continue;   // defensive
            epk[pos] = tmpCW[i];
        }
    }
}

// ---------------- fallback prologue kernels (R10, known-good) ----------------

__global__ void drop8_kernel(const float* __restrict__ x, ushort* __restrict__ y,
                             uint32_t k0, uint32_t k1, int n8) {
    int t = blockIdx.x * blockDim.x + threadIdx.x;
    if (t < n8) drop8_body(x, y, k0, k1, t);
}

__global__ void prep_w(const float* __restrict__ W1, const float* __restrict__ W2,
                       ushort* __restrict__ W1T, ushort* __restrict__ W2T) {
    int t = blockIdx.x * blockDim.x + threadIdx.x;
    if (t < 128 * 128 + 64 * 128) prepw_body(W1, W2, W1T, W2T, t);
}

__global__ void hist_kernel(const int* __restrict__ rows, int* __restrict__ deg) {
    int e = blockIdx.x * blockDim.x + threadIdx.x;
    if (e < N_EDGES) {
        int r = rows[e];
        if (r >= 0 && r < N_NODES) atomicAdd(&deg[r], 1);
    }
}

__global__ __launch_bounds__(CSR_BLK) void degsum_kernel(const int* __restrict__ deg,
                                                         int* __restrict__ blockSums) {
    __shared__ int red[CSR_BLK];
    int idx = blockIdx.x * CSR_BLK + threadIdx.x;
    red[threadIdx.x] = (idx < N_NODES) ? deg[idx] : 0;
    __syncthreads();
    for (int off = CSR_BLK / 2; off > 0; off >>= 1) {
        if (threadIdx.x < off) red[threadIdx.x] += red[threadIdx.x + off];
        __syncthreads();
    }
    if (threadIdx.x == 0) blockSums[blockIdx.x] = red[0];
}

__global__ __launch_bounds__(256) void scanblk_kernel(const int* __restrict__ blockSums,
                                                      int* __restrict__ blockOff) {
    __shared__ int s[256];
    int tid = threadIdx.x;
    s[tid] = (tid < CSR_NBLK) ? blockSums[tid] : 0;
    __syncthreads();
    for (int off = 1; off < 256; off <<= 1) {
        int t = (tid >= off) ? s[tid - off] : 0;
        __syncthreads();
        if (tid >= off) s[tid] += t;
        __syncthreads();
    }
    if (tid < CSR_NBLK) blockOff[tid] = (tid == 0) ? 0 : s[tid - 1];
}

__global__ __launch_bounds__(CSR_BLK) void scanfinal_kernel(const int* __restrict__ deg,
                                                            const int* __restrict__ blockOff,
                                                            int* __restrict__ start,
                                                            int* __restrict__ bcur) {
    __shared__ int s[CSR_BLK];
    int tid = threadIdx.x;
    int idx = blockIdx.x * CSR_BLK + tid;
    int d = (idx < N_NODES) ? deg[idx] : 0;
    s[tid] = d;
    __syncthreads();
    for (int off = 1; off < CSR_BLK; off <<= 1) {
        int t = (tid >= off) ? s[tid - off] : 0;
        __syncthreads();
        if (tid >= off) s[tid] += t;
        __syncthreads();
    }
    int incl = s[tid];
    int excl = incl - d;
    int boff = blockOff[blockIdx.x];
    if (idx < N_NODES) {
        int s0 = boff + excl;
        start[idx] = s0;
        if ((idx & 127) == 0) bcur[idx >> BSH] = s0;
        if (idx == N_NODES - 1) start[N_NODES] = boff + incl;
    }
}

__global__ __launch_bounds__(256) void bucket_scatter(const int* __restrict__ rows,
                                                      const int* __restrict__ cols,
                                                      const float* __restrict__ w,
                                                      int* __restrict__ bcur,
                                                      int* __restrict__ tmpRow,
                                                      int2* __restrict__ tmpCW) {
    __shared__ int hist[NBUCK];
    __shared__ int base[NBUCK];
    int e0 = blockIdx.x * EPB;
    for (int i = threadIdx.x; i < NBUCK; i += 256) hist[i] = 0;
    __syncthreads();
    int myrow[16];
#pragma unroll
    for (int k = 0; k < 16; ++k) {
        int e = e0 + k * 256 + threadIdx.x;
        int r = (e < N_EDGES) ? rows[e] : -1;
        if (r < 0 || r >= N_NODES) r = -1;
        myrow[k] = r;
        if (r >= 0) atomicAdd(&hist[r >> BSH], 1);
    }
    __syncthreads();
    for (int b = threadIdx.x; b < NBUCK; b += 256) {
        int c = hist[b];
        base[b] = (c > 0) ? atomicAdd(&bcur[b], c) : 0;
        hist[b] = 0;
    }
    __syncthreads();
#pragma unroll
    for (int k = 0; k < 16; ++k) {
        int r = myrow[k];
        if (r < 0) continue;
        int e = e0 + k * 256 + threadIdx.x;
        int b = r >> BSH;
        int pos = base[b] + atomicAdd(&hist[b], 1);
        if (pos < 0 || pos >= N_EDGES) continue;
        tmpRow[pos] = r;
        tmpCW[pos] = make_int2(cols[e], __float_as_int(w[e]));
    }
}

__global__ __launch_bounds__(256) void scatter2(const int* __restrict__ start,
                                                const int* __restrict__ tmpRow,
                                                const int2* __restrict__ tmpCW,
                                                int2* __restrict__ epk) {
    __shared__ int lcur[1 << BSH];
    int b = blockIdx.x;
    int r0 = b << BSH;
    int r1 = r0 + (1 << BSH);
    if (r1 > N_NODES) r1 = N_NODES;
    int nr = r1 - r0;
    for (int i = threadIdx.x; i < nr; i += 256) lcur[i] = start[r0 + i];
    __syncthreads();
    int e0 = start[r0], e1 = start[r1];
    for (int i = e0 + threadIdx.x; i < e1; i += 256) {
        int r = tmpRow[i];
        if (r < r0 || r >= r1) continue;
        int pos = atomicAdd(&lcur[r - r0], 1);
        if (pos < 0 || pos >= N_EDGES) continue;
        epk[pos] = tmpCW[i];
    }
}

// ---------------- SpMM 128-wide, bf16 gather -> bf16 out ----------------
__global__ __launch_bounds__(256) void spmm128_bf16(const int* __restrict__ start,
                                                    const int2* __restrict__ epk,
                                                    const ushort* __restrict__ hb,
                                                    ushort* __restrict__ outb) {
    int t = blockIdx.x * blockDim.x + threadIdx.x;
    int r = t >> 4;
    if (r >= N_NODES) return;
    int lane = t & 15;
    int s0 = start[r], s1 = start[r + 1];
    float a0[8] = {0.f, 0.f, 0.f, 0.f, 0.f, 0.f, 0.f, 0.f};
    float a1[8] = {0.f, 0.f, 0.f, 0.f, 0.f, 0.f, 0.f, 0.f};
    int i = s0;
    for (; i + 4 <= s1; i += 4) {
        int2 e0 = epk[i], e1 = epk[i + 1], e2 = epk[i + 2], e3 = epk[i + 3];
        uint4 u0 = *(const uint4*)(hb + (size_t)e0.x * D + lane * 8);
        uint4 u1 = *(const uint4*)(hb + (size_t)e1.x * D + lane * 8);
        uint4 u2 = *(const uint4*)(hb + (size_t)e2.x * D + lane * 8);
        uint4 u3 = *(const uint4*)(hb + (size_t)e3.x * D + lane * 8);
        fma8(a0, u0, __int_as_float(e0.y));
        fma8(a1, u1, __int_as_float(e1.y));
        fma8(a0, u2, __int_as_float(e2.y));
        fma8(a1, u3, __int_as_float(e3.y));
    }
    for (; i < s1; ++i) {
        int2 e = epk[i];
        uint4 u = *(const uint4*)(hb + (size_t)e.x * D + lane * 8);
        fma8(a0, u, __int_as_float(e.y));
    }
    uint4 o;
    o.x = f2bf(a0[0] + a1[0]) | (f2bf(a0[1] + a1[1]) << 16);
    o.y = f2bf(a0[2] + a1[2]) | (f2bf(a0[3] + a1[3]) << 16);
    o.z = f2bf(a0[4] + a1[4]) | (f2bf(a0[5] + a1[5]) << 16);
    o.w = f2bf(a0[6] + a1[6]) | (f2bf(a0[7] + a1[7]) << 16);
    *(uint4*)(outb + (size_t)r * D + lane * 8) = o;
}

// ---------------- SpMM 64-wide + bias, bf16 gather -> fp32 out ----------------
__global__ __launch_bounds__(256) void spmm64_bf16(const int* __restrict__ start,
                                                   const int2* __restrict__ epk,
                                                   const ushort* __restrict__ tb,
                                                   const float* __restrict__ b2,
                                                   float* __restrict__ out) {
    int t = blockIdx.x * blockDim.x + threadIdx.x;
    int r = t >> 3;
    if (r >= N_NODES) return;
    int lane = t & 7;
    int s0 = start[r], s1 = start[r + 1];
    float a0[8] = {0.f, 0.f, 0.f, 0.f, 0.f, 0.f, 0.f, 0.f};
    float a1[8] = {0.f, 0.f, 0.f, 0.f, 0.f, 0.f, 0.f, 0.f};
    int i = s0;
    for (; i + 4 <= s1; i += 4) {
        int2 e0 = epk[i], e1 = epk[i + 1], e2 = epk[i + 2], e3 = epk[i + 3];
        uint4 u0 = *(const uint4*)(tb + (size_t)e0.x * DOUT + lane * 8);
        uint4 u1 = *(const uint4*)(tb + (size_t)e1.x * DOUT + lane * 8);
        uint4 u2 = *(const uint4*)(tb + (size_t)e2.x * DOUT + lane * 8);
        uint4 u3 = *(const uint4*)(tb + (size_t)e3.x * DOUT + lane * 8);
        fma8(a0, u0, __int_as_float(e0.y));
        fma8(a1, u1, __int_as_float(e1.y));
        fma8(a0, u2, __int_as_float(e2.y));
        fma8(a1, u3, __int_as_float(e3.y));
    }
    for (; i < s1; ++i) {
        int2 e = epk[i];
        uint4 u = *(const uint4*)(tb + (size_t)e.x * DOUT + lane * 8);
        fma8(a0, u, __int_as_float(e.y));
    }
    float4 blo = *(const float4*)(b2 + lane * 8);
    float4 bhi = *(const float4*)(b2 + lane * 8 + 4);
    float* op = out + (size_t)r * DOUT + lane * 8;
    *(float4*)(op + 0) = make_float4(a0[0] + a1[0] + blo.x, a0[1] + a1[1] + blo.y,
                                     a0[2] + a1[2] + blo.z, a0[3] + a1[3] + blo.w);
    *(float4*)(op + 4) = make_float4(a0[4] + a1[4] + bhi.x, a0[5] + a1[5] + bhi.y,
                                     a0[6] + a1[6] + bhi.z, a0[7] + a1[7] + bhi.w);
}

// ---------------- fused MFMA lin1+lin2 ----------------
#define LROW 136
__global__ __launch_bounds__(256) void lin12_mfma(const ushort* __restrict__ Bb,
                                                  const ushort* __restrict__ W1T,
                                                  const float* __restrict__ b1,
                                                  const ushort* __restrict__ W2T,
                                                  ushort* __restrict__ T,
                                                  uint32_t k0, uint32_t k1) {
    __shared__ ushort h1[4][16][LROW];
    int wave = threadIdx.x >> 6;
    int lane = threadIdx.x & 63;
    int lrow = lane & 15;
    int lhk  = lane >> 4;
    int rowBase = blockIdx.x * 64 + wave * 16;

    int arow = rowBase + lrow;
    if (arow >= N_NODES) arow = N_NODES - 1;
    const ushort* aptr = Bb + (size_t)arow * D + lhk * 8;
    bf16x8 afrag[4];
#pragma unroll
    for (int kb = 0; kb < 4; ++kb)
        afrag[kb] = *(const bf16x8*)(aptr + kb * 32);

    f32x4 acc[8];
#pragma unroll
    for (int nt = 0; nt < 8; ++nt) acc[nt] = (f32x4){0.f, 0.f, 0.f, 0.f};
#pragma unroll
    for (int nt = 0; nt < 8; ++nt) {
        const ushort* wp = W1T + (size_t)(nt * 16 + lrow) * 128 + lhk * 8;
#pragma unroll
        for (int kb = 0; kb < 4; ++kb) {
            bf16x8 bfrag = *(const bf16x8*)(wp + kb * 32);
            acc[nt] = __builtin_amdgcn_mfma_f32_16x16x32_bf16(afrag[kb], bfrag, acc[nt], 0, 0, 0);
        }
    }

#pragma unroll
    for (int nt = 0; nt < 8; ++nt) {
        int c = nt * 16 + lrow;
        float bias = b1[c];
#pragma unroll
        for (int v = 0; v < 4; ++v) {
            int rl = lhk * 4 + v;
            int row = rowBase + rl;
            float x = fmaxf(acc[nt][v] + bias, 0.f);
            uint32_t j = (uint32_t)row * 128u + (uint32_t)c;
            x = keep_mask(k0, k1, j) ? x * 2.f : 0.f;
            h1[wave][rl][c] = (ushort)f2bf(x);
        }
    }
    __syncthreads();

    bf16x8 a2[4];
#pragma unroll
    for (int kb = 0; kb < 4; ++kb)
        a2[kb] = *(const bf16x8*)&h1[wave][lrow][lhk * 8 + kb * 32];

    f32x4 acc2[4];
#pragma unroll
    for (int nt = 0; nt < 4; ++nt) acc2[nt] = (f32x4){0.f, 0.f, 0.f, 0.f};
#pragma unroll
    for (int nt = 0; nt < 4; ++nt) {
        const ushort* wp = W2T + (size_t)(nt * 16 + lrow) * 128 + lhk * 8;
#pragma unroll
        for (int kb = 0; kb < 4; ++kb) {
            bf16x8 bfrag = *(const bf16x8*)(wp + kb * 32);
            acc2[nt] = __builtin_amdgcn_mfma_f32_16x16x32_bf16(a2[kb], bfrag, acc2[nt], 0, 0, 0);
        }
    }

#pragma unroll
    for (int nt = 0; nt < 4; ++nt) {
        int c = nt * 16 + lrow;
#pragma unroll
        for (int v = 0; v < 4; ++v) {
            int row = rowBase + lhk * 4 + v;
            if (row < N_NODES)
                T[(size_t)row * DOUT + c] = (ushort)f2bf(acc2[nt][v]);
        }
    }
}

extern "C" void kernel_launch(void* const* d_in, const int* in_sizes, int n_in,
                              void* d_out, int out_size, void* d_ws, size_t ws_size,
                              hipStream_t stream) {
    const int*   rows = (const int*)d_in[0];
    const int*   cols = (const int*)d_in[1];
    const float* w    = (const float*)d_in[2];
    const float* X    = (const float*)d_in[3];
    const float* W1   = (const float*)d_in[4];
    const float* b1   = (const float*)d_in[5];
    const float* W2   = (const float*)d_in[6];
    const float* b2   = (const float*)d_in[7];
    float* out = (float*)d_out;

    uint32_t ka0, ka1, kb0, kb1;
    threefry2x32(0u, 42u, 0u, 0u, ka0, ka1);  // k1 (drop1)
    threefry2x32(0u, 42u, 0u, 1u, kb0, kb1);  // k2 (drop2)

    // workspace layout
    char* p = (char*)d_ws;
    ushort* Bb        = (ushort*)p;            p += (size_t)N_NODES * D * 2;
    ushort* Xb        = (ushort*)p;            p += (size_t)N_NODES * D * 2;
    ushort* T         = (ushort*)p;            p += (size_t)N_NODES * DOUT * 2;
    int2*   epk       = (int2*)p;              p += (size_t)N_EDGES * 8;
    int2*   tmpCW     = (int2*)p;              p += (size_t)N_EDGES * 8;
    int*    tmpRow    = (int*)p;               p += (size_t)N_EDGES * 4;
    ushort* W1T       = (ushort*)p;            p += (size_t)128 * 128 * 2;
    ushort* W2T       = (ushort*)p;            p += (size_t)64 * 128 * 2;
    int*    start     = (int*)p;               p += (size_t)(N_NODES + 1) * 4;
    int*    deg       = (int*)p;               p += (size_t)N_NODES * 4;
    int*    bcur      = (int*)p;               p += (size_t)NBUCK * 4;
    int*    blockSums = (int*)p;               p += (size_t)CSR_NBLK * 4;
    int*    blockOff  = (int*)p;               p += (size_t)CSR_NBLK * 4;

    // ---- prologue: single cooperative kernel (fallback: R10 sequence) ----
    void* args[] = {
        (void*)&rows, (void*)&cols, (void*)&w, (void*)&X, (void*)&W1, (void*)&W2,
        (void*)&Xb, (void*)&W1T, (void*)&W2T,
        (void*)&deg, (void*)&blockSums, (void*)&blockOff, (void*)&start, (void*)&bcur,
        (void*)&tmpRow, (void*)&tmpCW, (void*)&epk,
        (void*)&ka0, (void*)&ka1
    };
    hipError_t cerr = hipLaunchCooperativeKernel((const void*)csr_coop,
                                                 dim3(SC_NBLK), dim3(256),
                                                 args, 0, stream);
    if (cerr != hipSuccess) {
        // fallback: multi-kernel prologue (identical math)
        int n8 = N_NODES * D / 8;
        hipMemsetAsync(deg, 0, (size_t)N_NODES * 4, stream);
        drop8_kernel<<<(n8 + 255) / 256, 256, 0, stream>>>(X, Xb, ka0, ka1, n8);
        prep_w<<<(128 * 128 + 64 * 128 + 255) / 256, 256, 0, stream>>>(W1, W2, W1T, W2T);
        hist_kernel<<<(N_EDGES + 255) / 256, 256, 0, stream>>>(rows, deg);
        degsum_kernel<<<CSR_NBLK, CSR_BLK, 0, stream>>>(deg, blockSums);
        scanblk_kernel<<<1, 256, 0, stream>>>(blockSums, blockOff);
        scanfinal_kernel<<<CSR_NBLK, CSR_BLK, 0, stream>>>(deg, blockOff, start, bcur);
        bucket_scatter<<<SC_NBLK, 256, 0, stream>>>(rows, cols, w, bcur, tmpRow, tmpCW);
        scatter2<<<NBUCK, 256, 0, stream>>>(start, tmpRow, tmpCW, epk);
    }

    // ---- forward ----
    spmm128_bf16<<<((size_t)N_NODES * 16 + 255) / 256, 256, 0, stream>>>(start, epk, Xb, Bb);
    lin12_mfma<<<(N_NODES + 63) / 64, 256, 0, stream>>>(Bb, W1T, b1, W2T, T, kb0, kb1);
    spmm64_bf16<<<((size_t)N_NODES * 8 + 255) / 256, 256, 0, stream>>>(start, epk, T, b2, out);
}

// Round 13
// 168.799 us; speedup vs baseline: 1.9340x; 1.9340x over previous
//
#include <hip/hip_runtime.h>
#include <stdint.h>

#define N_NODES 50000
#define N_EDGES 800000
#define D 128
#define DOUT 64

#define CSR_BLK 256
#define CSR_NBLK ((N_NODES + CSR_BLK - 1) / CSR_BLK)  // 196

#define BSH 7                                  // rows per bucket = 128
#define NBUCK ((N_NODES + 127) >> BSH)         // 391
#define EPB 4096                               // edges per bucket_scatter block
#define SC_NBLK ((N_EDGES + EPB - 1) / EPB)    // 196

typedef short bf16x8 __attribute__((ext_vector_type(8)));
typedef float f32x4 __attribute__((ext_vector_type(4)));

__host__ __device__ inline uint32_t rotl32(uint32_t v, int d) {
    return (v << d) | (v >> (32 - d));
}

// JAX threefry2x32 (20 rounds), matches jax/_src/prng.py
__host__ __device__ inline void threefry2x32(uint32_t k0, uint32_t k1,
                                             uint32_t x0, uint32_t x1,
                                             uint32_t& o0, uint32_t& o1) {
    uint32_t ks2 = 0x1BD11BDAu ^ k0 ^ k1;
    x0 += k0; x1 += k1;
#define TFR(d) { x0 += x1; x1 = rotl32(x1, d); x1 ^= x0; }
    TFR(13) TFR(15) TFR(26) TFR(6)
    x0 += k1;  x1 += ks2 + 1u;
    TFR(17) TFR(29) TFR(16) TFR(24)
    x0 += ks2; x1 += k0 + 2u;
    TFR(13) TFR(15) TFR(26) TFR(6)
    x0 += k0;  x1 += k1 + 3u;
    TFR(17) TFR(29) TFR(16) TFR(24)
    x0 += k1;  x1 += ks2 + 4u;
    TFR(13) TFR(15) TFR(26) TFR(6)
    x0 += ks2; x1 += k0 + 5u;
#undef TFR
    o0 = x0; o1 = x1;
}

__device__ inline bool keep_mask(uint32_t k0, uint32_t k1, uint32_t j) {
    uint32_t b0, b1;
    threefry2x32(k0, k1, 0u, j, b0, b1);
    uint32_t bits = b0 ^ b1;
    float u = __uint_as_float((bits >> 9) | 0x3f800000u) - 1.0f;
    return u < 0.5f;
}

__device__ inline uint32_t f2bf(float f) {
    uint32_t u = __float_as_uint(f);
    return (u + 0x7fffu + ((u >> 16) & 1u)) >> 16;
}
__device__ inline float bf2f_lo(uint32_t u) { return __uint_as_float(u << 16); }
__device__ inline float bf2f_hi(uint32_t u) { return __uint_as_float(u & 0xffff0000u); }

__device__ inline void fma8(float* a, uint4 u, float w) {
    a[0] = fmaf(w, bf2f_lo(u.x), a[0]);
    a[1] = fmaf(w, bf2f_hi(u.x), a[1]);
    a[2] = fmaf(w, bf2f_lo(u.y), a[2]);
    a[3] = fmaf(w, bf2f_hi(u.y), a[3]);
    a[4] = fmaf(w, bf2f_lo(u.z), a[4]);
    a[5] = fmaf(w, bf2f_hi(u.z), a[5]);
    a[6] = fmaf(w, bf2f_lo(u.w), a[6]);
    a[7] = fmaf(w, bf2f_hi(u.w), a[7]);
}

// ---------------- fused0: dropout(X)->bf16 | weight transpose | degree hist ----------------
__global__ void fused0_kernel(const float* __restrict__ X, ushort* __restrict__ Xb,
                              const float* __restrict__ W1, const float* __restrict__ W2,
                              ushort* __restrict__ W1T, ushort* __restrict__ W2T,
                              const int* __restrict__ rows, int* __restrict__ deg,
                              uint32_t k0, uint32_t k1) {
    int t = blockIdx.x * blockDim.x + threadIdx.x;
    // task 1: dropout (800000 uint4 groups)
    if (t < N_NODES * D / 8) {
        float4 v0 = ((const float4*)X)[t * 2];
        float4 v1 = ((const float4*)X)[t * 2 + 1];
        uint32_t j = (uint32_t)t * 8u;
        float f[8] = {v0.x, v0.y, v0.z, v0.w, v1.x, v1.y, v1.z, v1.w};
        uint32_t o[4];
#pragma unroll
        for (int p = 0; p < 4; ++p) {
            float a = keep_mask(k0, k1, j + 2 * p)     ? f[2 * p] * 2.f     : 0.f;
            float b = keep_mask(k0, k1, j + 2 * p + 1) ? f[2 * p + 1] * 2.f : 0.f;
            o[p] = f2bf(a) | (f2bf(b) << 16);
        }
        ((uint4*)Xb)[t] = make_uint4(o[0], o[1], o[2], o[3]);
    }
    // task 2: weight transpose+cast (24576 elems)
    if (t < 128 * 128 + 64 * 128) {
        if (t < 128 * 128) {
            int n = t >> 7, k = t & 127;
            W1T[n * 128 + k] = (ushort)f2bf(W1[k * 128 + n]);
        } else {
            int u = t - 128 * 128;
            int n = u >> 7, k = u & 127;
            W2T[n * 128 + k] = (ushort)f2bf(W2[k * 64 + n]);
        }
    }
    // task 3: degree histogram (800000 edges)
    if (t < N_EDGES) {
        int r = rows[t];
        if (r >= 0 && r < N_NODES) atomicAdd(&deg[r], 1);
    }
}

// ---------------- CSR build ----------------

__global__ __launch_bounds__(CSR_BLK) void degsum_kernel(const int* __restrict__ deg,
                                                         int* __restrict__ blockSums) {
    __shared__ int red[CSR_BLK];
    int idx = blockIdx.x * CSR_BLK + threadIdx.x;
    red[threadIdx.x] = (idx < N_NODES) ? deg[idx] : 0;
    __syncthreads();
    for (int off = CSR_BLK / 2; off > 0; off >>= 1) {
        if (threadIdx.x < off) red[threadIdx.x] += red[threadIdx.x + off];
        __syncthreads();
    }
    if (threadIdx.x == 0) blockSums[blockIdx.x] = red[0];
}

__global__ __launch_bounds__(256) void scanblk_kernel(const int* __restrict__ blockSums,
                                                      int* __restrict__ blockOff) {
    __shared__ int s[256];
    int tid = threadIdx.x;
    s[tid] = (tid < CSR_NBLK) ? blockSums[tid] : 0;
    __syncthreads();
    for (int off = 1; off < 256; off <<= 1) {
        int t = (tid >= off) ? s[tid - off] : 0;
        __syncthreads();
        if (tid >= off) s[tid] += t;
        __syncthreads();
    }
    if (tid < CSR_NBLK) blockOff[tid] = (tid == 0) ? 0 : s[tid - 1];
}

__global__ __launch_bounds__(CSR_BLK) void scanfinal_kernel(const int* __restrict__ deg,
                                                            const int* __restrict__ blockOff,
                                                            int* __restrict__ start,
                                                            int* __restrict__ bcur) {
    __shared__ int s[CSR_BLK];
    int tid = threadIdx.x;
    int idx = blockIdx.x * CSR_BLK + tid;
    int d = (idx < N_NODES) ? deg[idx] : 0;
    s[tid] = d;
    __syncthreads();
    for (int off = 1; off < CSR_BLK; off <<= 1) {
        int t = (tid >= off) ? s[tid - off] : 0;
        __syncthreads();
        if (tid >= off) s[tid] += t;
        __syncthreads();
    }
    int incl = s[tid];
    int excl = incl - d;
    int boff = blockOff[blockIdx.x];
    if (idx < N_NODES) {
        int s0 = boff + excl;
        start[idx] = s0;
        if ((idx & 127) == 0) bcur[idx >> BSH] = s0;
        if (idx == N_NODES - 1) start[N_NODES] = boff + incl;
    }
}

__global__ __launch_bounds__(256) void bucket_scatter(const int* __restrict__ rows,
                                                      const int* __restrict__ cols,
                                                      const float* __restrict__ w,
                                                      int* __restrict__ bcur,
                                                      int* __restrict__ tmpRow,
                                                      int2* __restrict__ tmpCW) {
    __shared__ int hist[NBUCK];
    __shared__ int base[NBUCK];
    int e0 = blockIdx.x * EPB;
    for (int i = threadIdx.x; i < NBUCK; i += 256) hist[i] = 0;
    __syncthreads();
    int myrow[16];
#pragma unroll
    for (int k = 0; k < 16; ++k) {
        int e = e0 + k * 256 + threadIdx.x;
        int r = (e < N_EDGES) ? rows[e] : -1;
        if (r < 0 || r >= N_NODES) r = -1;
        myrow[k] = r;
        if (r >= 0) atomicAdd(&hist[r >> BSH], 1);
    }
    __syncthreads();
    for (int b = threadIdx.x; b < NBUCK; b += 256) {
        int c = hist[b];
        base[b] = (c > 0) ? atomicAdd(&bcur[b], c) : 0;
        hist[b] = 0;
    }
    __syncthreads();
#pragma unroll
    for (int k = 0; k < 16; ++k) {
        int r = myrow[k];
        if (r < 0) continue;
        int e = e0 + k * 256 + threadIdx.x;
        int b = r >> BSH;
        int pos = base[b] + atomicAdd(&hist[b], 1);
        if (pos < 0 || pos >= N_EDGES) continue;
        tmpRow[pos] = r;
        tmpCW[pos] = make_int2(cols[e], __float_as_int(w[e]));
    }
}

__global__ __launch_bounds__(256) void scatter2(const int* __restrict__ start,
                                                const int* __restrict__ tmpRow,
                                                const int2* __restrict__ tmpCW,
                                                int2* __restrict__ epk) {
    __shared__ int lcur[1 << BSH];
    int b = blockIdx.x;
    int r0 = b << BSH;
    int r1 = r0 + (1 << BSH);
    if (r1 > N_NODES) r1 = N_NODES;
    int nr = r1 - r0;
    for (int i = threadIdx.x; i < nr; i += 256) lcur[i] = start[r0 + i];
    __syncthreads();
    int e0 = start[r0], e1 = start[r1];
    for (int i = e0 + threadIdx.x; i < e1; i += 256) {
        int r = tmpRow[i];
        if (r < r0 || r >= r1) continue;
        int pos = atomicAdd(&lcur[r - r0], 1);
        if (pos < 0 || pos >= N_EDGES) continue;
        epk[pos] = tmpCW[i];
    }
}

// ---------------- fused SpMM(128) + MFMA MLP ----------------
// Per block: 64 rows. Phase A: gather-SpMM (16 lanes/row, 4 row-groups) -> bf16 LDS.
// Phase B: GEMM1(W1)+bias+relu+dropout -> LDS -> GEMM2(W2) -> T (bf16).
#define LROW 136
__global__ __launch_bounds__(256) void spmm_mlp(const int* __restrict__ start,
                                                const int2* __restrict__ epk,
                                                const ushort* __restrict__ Xb,
                                                const ushort* __restrict__ W1T,
                                                const float* __restrict__ b1,
                                                const ushort* __restrict__ W2T,
                                                ushort* __restrict__ T,
                                                uint32_t k0, uint32_t k1) {
    __shared__ ushort h0[64][LROW];      // SpMM output tile (bf16)
    __shared__ ushort h1[4][16][LROW];   // hidden tile (bf16)
    int tid = threadIdx.x;
    int rowBase = blockIdx.x * 64;

    // ---- Phase A: SpMM for this block's 64 rows ----
    {
        int lane = tid & 15;
        int rsub = tid >> 4;   // 0..15
#pragma unroll
        for (int rg = 0; rg < 4; ++rg) {
            int lr = rg * 16 + rsub;
            int r = rowBase + lr;
            float a0[8] = {0.f, 0.f, 0.f, 0.f, 0.f, 0.f, 0.f, 0.f};
            float a1[8] = {0.f, 0.f, 0.f, 0.f, 0.f, 0.f, 0.f, 0.f};
            if (r < N_NODES) {
                int s0 = start[r], s1 = start[r + 1];
                int i = s0;
                for (; i + 4 <= s1; i += 4) {
                    int2 e0 = epk[i], e1 = epk[i + 1], e2 = epk[i + 2], e3 = epk[i + 3];
                    uint4 u0 = *(const uint4*)(Xb + (size_t)e0.x * D + lane * 8);
                    uint4 u1 = *(const uint4*)(Xb + (size_t)e1.x * D + lane * 8);
                    uint4 u2 = *(const uint4*)(Xb + (size_t)e2.x * D + lane * 8);
                    uint4 u3 = *(const uint4*)(Xb + (size_t)e3.x * D + lane * 8);
                    fma8(a0, u0, __int_as_float(e0.y));
                    fma8(a1, u1, __int_as_float(e1.y));
                    fma8(a0, u2, __int_as_float(e2.y));
                    fma8(a1, u3, __int_as_float(e3.y));
                }
                for (; i < s1; ++i) {
                    int2 e = epk[i];
                    uint4 u = *(const uint4*)(Xb + (size_t)e.x * D + lane * 8);
                    fma8(a0, u, __int_as_float(e.y));
                }
            }
            uint4 o;
            o.x = f2bf(a0[0] + a1[0]) | (f2bf(a0[1] + a1[1]) << 16);
            o.y = f2bf(a0[2] + a1[2]) | (f2bf(a0[3] + a1[3]) << 16);
            o.z = f2bf(a0[4] + a1[4]) | (f2bf(a0[5] + a1[5]) << 16);
            o.w = f2bf(a0[6] + a1[6]) | (f2bf(a0[7] + a1[7]) << 16);
            *(uint4*)&h0[lr][lane * 8] = o;
        }
    }
    __syncthreads();

    // ---- Phase B: MFMA MLP (identical math to lin12_mfma, A-frags from LDS) ----
    int wave = tid >> 6;
    int lane = tid & 63;
    int lrow = lane & 15;
    int lhk  = lane >> 4;
    int rowB = rowBase + wave * 16;

    bf16x8 afrag[4];
#pragma unroll
    for (int kb = 0; kb < 4; ++kb)
        afrag[kb] = *(const bf16x8*)&h0[wave * 16 + lrow][lhk * 8 + kb * 32];

    f32x4 acc[8];
#pragma unroll
    for (int nt = 0; nt < 8; ++nt) acc[nt] = (f32x4){0.f, 0.f, 0.f, 0.f};
#pragma unroll
    for (int nt = 0; nt < 8; ++nt) {
        const ushort* wp = W1T + (size_t)(nt * 16 + lrow) * 128 + lhk * 8;
#pragma unroll
        for (int kb = 0; kb < 4; ++kb) {
            bf16x8 bfrag = *(const bf16x8*)(wp + kb * 32);
            acc[nt] = __builtin_amdgcn_mfma_f32_16x16x32_bf16(afrag[kb], bfrag, acc[nt], 0, 0, 0);
        }
    }

#pragma unroll
    for (int nt = 0; nt < 8; ++nt) {
        int c = nt * 16 + lrow;
        float bias = b1[c];
#pragma unroll
        for (int v = 0; v < 4; ++v) {
            int rl = lhk * 4 + v;
            int row = rowB + rl;
            float x = fmaxf(acc[nt][v] + bias, 0.f);
            uint32_t j = (uint32_t)row * 128u + (uint32_t)c;
            x = keep_mask(k0, k1, j) ? x * 2.f : 0.f;
            h1[wave][rl][c] = (ushort)f2bf(x);
        }
    }
    __syncthreads();

    bf16x8 a2[4];
#pragma unroll
    for (int kb = 0; kb < 4; ++kb)
        a2[kb] = *(const bf16x8*)&h1[wave][lrow][lhk * 8 + kb * 32];

    f32x4 acc2[4];
#pragma unroll
    for (int nt = 0; nt < 4; ++nt) acc2[nt] = (f32x4){0.f, 0.f, 0.f, 0.f};
#pragma unroll
    for (int nt = 0; nt < 4; ++nt) {
        const ushort* wp = W2T + (size_t)(nt * 16 + lrow) * 128 + lhk * 8;
#pragma unroll
        for (int kb = 0; kb < 4; ++kb) {
            bf16x8 bfrag = *(const bf16x8*)(wp + kb * 32);
            acc2[nt] = __builtin_amdgcn_mfma_f32_16x16x32_bf16(a2[kb], bfrag, acc2[nt], 0, 0, 0);
        }
    }

#pragma unroll
    for (int nt = 0; nt < 4; ++nt) {
        int c = nt * 16 + lrow;
#pragma unroll
        for (int v = 0; v < 4; ++v) {
            int row = rowB + lhk * 4 + v;
            if (row < N_NODES)
                T[(size_t)row * DOUT + c] = (ushort)f2bf(acc2[nt][v]);
        }
    }
}

// ---------------- SpMM 64-wide + bias, bf16 gather -> fp32 out ----------------
__global__ __launch_bounds__(256) void spmm64_bf16(const int* __restrict__ start,
                                                   const int2* __restrict__ epk,
                                                   const ushort* __restrict__ tb,
                                                   const float* __restrict__ b2,
                                                   float* __restrict__ out) {
    int t = blockIdx.x * blockDim.x + threadIdx.x;
    int r = t >> 3;
    if (r >= N_NODES) return;
    int lane = t & 7;
    int s0 = start[r], s1 = start[r + 1];
    float a0[8] = {0.f, 0.f, 0.f, 0.f, 0.f, 0.f, 0.f, 0.f};
    float a1[8] = {0.f, 0.f, 0.f, 0.f, 0.f, 0.f, 0.f, 0.f};
    int i = s0;
    for (; i + 4 <= s1; i += 4) {
        int2 e0 = epk[i], e1 = epk[i + 1], e2 = epk[i + 2], e3 = epk[i + 3];
        uint4 u0 = *(const uint4*)(tb + (size_t)e0.x * DOUT + lane * 8);
        uint4 u1 = *(const uint4*)(tb + (size_t)e1.x * DOUT + lane * 8);
        uint4 u2 = *(const uint4*)(tb + (size_t)e2.x * DOUT + lane * 8);
        uint4 u3 = *(const uint4*)(tb + (size_t)e3.x * DOUT + lane * 8);
        fma8(a0, u0, __int_as_float(e0.y));
        fma8(a1, u1, __int_as_float(e1.y));
        fma8(a0, u2, __int_as_float(e2.y));
        fma8(a1, u3, __int_as_float(e3.y));
    }
    for (; i < s1; ++i) {
        int2 e = epk[i];
        uint4 u = *(const uint4*)(tb + (size_t)e.x * DOUT + lane * 8);
        fma8(a0, u, __int_as_float(e.y));
    }
    float4 blo = *(const float4*)(b2 + lane * 8);
    float4 bhi = *(const float4*)(b2 + lane * 8 + 4);
    float* op = out + (size_t)r * DOUT + lane * 8;
    *(float4*)(op + 0) = make_float4(a0[0] + a1[0] + blo.x, a0[1] + a1[1] + blo.y,
                                     a0[2] + a1[2] + blo.z, a0[3] + a1[3] + blo.w);
    *(float4*)(op + 4) = make_float4(a0[4] + a1[4] + bhi.x, a0[5] + a1[5] + bhi.y,
                                     a0[6] + a1[6] + bhi.z, a0[7] + a1[7] + bhi.w);
}

extern "C" void kernel_launch(void* const* d_in, const int* in_sizes, int n_in,
                              void* d_out, int out_size, void* d_ws, size_t ws_size,
                              hipStream_t stream) {
    const int*   rows = (const int*)d_in[0];
    const int*   cols = (const int*)d_in[1];
    const float* w    = (const float*)d_in[2];
    const float* X    = (const float*)d_in[3];
    const float* W1   = (const float*)d_in[4];
    const float* b1   = (const float*)d_in[5];
    const float* W2   = (const float*)d_in[6];
    const float* b2   = (const float*)d_in[7];
    float* out = (float*)d_out;

    uint32_t ka0, ka1, kb0, kb1;
    threefry2x32(0u, 42u, 0u, 0u, ka0, ka1);  // k1 (drop1)
    threefry2x32(0u, 42u, 0u, 1u, kb0, kb1);  // k2 (drop2)

    // workspace layout
    char* p = (char*)d_ws;
    ushort* Xb        = (ushort*)p;            p += (size_t)N_NODES * D * 2;
    ushort* T         = (ushort*)p;            p += (size_t)N_NODES * DOUT * 2;
    int2*   epk       = (int2*)p;              p += (size_t)N_EDGES * 8;
    int2*   tmpCW     = (int2*)p;              p += (size_t)N_EDGES * 8;
    int*    tmpRow    = (int*)p;               p += (size_t)N_EDGES * 4;
    ushort* W1T       = (ushort*)p;            p += (size_t)128 * 128 * 2;
    ushort* W2T       = (ushort*)p;            p += (size_t)64 * 128 * 2;
    int*    start     = (int*)p;               p += (size_t)(N_NODES + 1) * 4;
    int*    deg       = (int*)p;               p += (size_t)N_NODES * 4;
    int*    bcur      = (int*)p;               p += (size_t)NBUCK * 4;
    int*    blockSums = (int*)p;               p += (size_t)CSR_NBLK * 4;
    int*    blockOff  = (int*)p;               p += (size_t)CSR_NBLK * 4;

    // ---- prologue (wide grids, merged where independent) ----
    hipMemsetAsync(deg, 0, (size_t)N_NODES * 4, stream);
    fused0_kernel<<<(N_EDGES + 255) / 256, 256, 0, stream>>>(X, Xb, W1, W2, W1T, W2T,
                                                             rows, deg, ka0, ka1);
    degsum_kernel<<<CSR_NBLK, CSR_BLK, 0, stream>>>(deg, blockSums);
    scanblk_kernel<<<1, 256, 0, stream>>>(blockSums, blockOff);
    scanfinal_kernel<<<CSR_NBLK, CSR_BLK, 0, stream>>>(deg, blockOff, start, bcur);
    bucket_scatter<<<SC_NBLK, 256, 0, stream>>>(rows, cols, w, bcur, tmpRow, tmpCW);
    scatter2<<<NBUCK, 256, 0, stream>>>(start, tmpRow, tmpCW, epk);

    // ---- forward ----
    spmm_mlp<<<(N_NODES + 63) / 64, 256, 0, stream>>>(start, epk, Xb, W1T, b1, W2T, T, kb0, kb1);
    spmm64_bf16<<<((size_t)N_NODES * 8 + 255) / 256, 256, 0, stream>>>(start, epk, T, b2, out);
}